// Round 8
// baseline (719.050 us; speedup 1.0000x reference)
//
#include <hip/hip_runtime.h>

#define CDIM 512
#define NDIM 4096
#define BATCH 4

using bf8v = __attribute__((ext_vector_type(8))) __bf16;
using f4v  = __attribute__((ext_vector_type(4))) float;

static __device__ __forceinline__ unsigned short f2bf(float f) {
  unsigned int u = __float_as_uint(f);
  u += 0x7fffu + ((u >> 16) & 1u);   // round-to-nearest-even
  return (unsigned short)(u >> 16);
}

// ---------------- GN pass 1: per-(b,g) mean/rstd ----------------
__global__ __launch_bounds__(256) void gn_stats_kernel(
    const float* __restrict__ x, float* __restrict__ stats) {
  const int tid = threadIdx.x;
  const float4* xv = (const float4*)(x + (long)blockIdx.x * 65536);
  float s = 0.f, ss = 0.f;
  for (int i = tid; i < 16384; i += 256) {
    float4 d = xv[i];
    s  += d.x + d.y + d.z + d.w;
    ss += d.x * d.x + d.y * d.y + d.z * d.z + d.w * d.w;
  }
#pragma unroll
  for (int off = 32; off; off >>= 1) {
    s  += __shfl_down(s, off);
    ss += __shfl_down(ss, off);
  }
  __shared__ float red[8];
  if ((tid & 63) == 0) { red[tid >> 6] = s; red[4 + (tid >> 6)] = ss; }
  __syncthreads();
  if (tid == 0) {
    float S  = red[0] + red[1] + red[2] + red[3];
    float SS = red[4] + red[5] + red[6] + red[7];
    float mean = S * (1.f / 65536.f);
    float var  = SS * (1.f / 65536.f) - mean * mean;
    stats[blockIdx.x * 2]     = mean;
    stats[blockIdx.x * 2 + 1] = rsqrtf(var + 1e-6f);
  }
}

// ---------------- GN pass 2: normalize + transpose, fp32 [C,N] -> bf16 [N,C] ----------------
__global__ __launch_bounds__(256) void gn_transpose_kernel(
    const float* __restrict__ x, const float* __restrict__ gs,
    const float* __restrict__ gb, const float* __restrict__ stats,
    unsigned short* __restrict__ hT) {
  __shared__ float t[64][65];
  const int tid = threadIdx.x;
  const int b = blockIdx.z;
  const long bbx = (long)b * ((long)CDIM * NDIM);
  const int n0 = blockIdx.x * 64, c0 = blockIdx.y * 64;
  for (int k = 0; k < 4; ++k) {
    int it = tid + k * 256;
    int c = it >> 4, no = (it & 15) << 2;
    int ch = c0 + c;
    int g = ch >> 4;
    float mean = stats[(b * 32 + g) * 2];
    float rstd = stats[(b * 32 + g) * 2 + 1];
    float a  = rstd * gs[ch];
    float bb = gb[ch] - mean * a;
    float4 d = *(const float4*)&x[bbx + (long)ch * NDIM + n0 + no];
    t[no + 0][c] = d.x * a + bb;
    t[no + 1][c] = d.y * a + bb;
    t[no + 2][c] = d.z * a + bb;
    t[no + 3][c] = d.w * a + bb;
  }
  __syncthreads();
  const long bbh = (long)b * ((long)NDIM * CDIM);
  for (int k = 0; k < 2; ++k) {
    int it = tid + k * 256;
    int n = it >> 3, co = (it & 7) << 3;
    unsigned int ow[4];
#pragma unroll
    for (int j = 0; j < 4; ++j) {
      unsigned short lo = f2bf(t[n][co + 2 * j]);
      unsigned short hi = f2bf(t[n][co + 2 * j + 1]);
      ow[j] = (unsigned int)lo | ((unsigned int)hi << 16);
    }
    uint4 o; o.x = ow[0]; o.y = ow[1]; o.z = ow[2]; o.w = ow[3];
    *(uint4*)&hT[bbh + (long)(n0 + n) * CDIM + c0 + co] = o;
  }
}

// ---------------- merged prep: wq/wk/wv fp32->bf16 + bias concat ----------------
__global__ __launch_bounds__(256) void prep_kernel(
    const float* __restrict__ wq, const float* __restrict__ wk,
    const float* __restrict__ wv, const float* __restrict__ bq,
    const float* __restrict__ bk, unsigned short* __restrict__ wqkb,
    unsigned short* __restrict__ wvb, float* __restrict__ bqk) {
  int blk = blockIdx.x;
  if (blk < 768) {
    int i = blk * 256 + threadIdx.x;
    const float* src = (blk < 256) ? wq : (blk < 512) ? wk : wv;
    unsigned short* dst = (blk < 256) ? wqkb : (blk < 512) ? (wqkb + 262144) : wvb;
    int j = i - ((blk < 256) ? 0 : (blk < 512) ? 65536 : 131072);
    float4 d = ((const float4*)src)[j];
    ushort4 o;
    o.x = f2bf(d.x); o.y = f2bf(d.y); o.z = f2bf(d.z); o.w = f2bf(d.w);
    ((ushort4*)dst)[j] = o;
  } else {
#pragma unroll
    for (int k = 0; k < 4; ++k) {
      int i = threadIdx.x + k * 256;
      bqk[i] = (i < 512) ? bq[i] : bk[i - 512];
    }
  }
}

// ---------------- fp32 -> bf16 convert (wp, launched late) ----------------
__global__ __launch_bounds__(256) void cvt_kernel(
    const float* __restrict__ src, unsigned short* __restrict__ dst, int n4) {
  int i = blockIdx.x * 256 + threadIdx.x;
  if (i >= n4) return;
  float4 d = ((const float4*)src)[i];
  ushort4 o;
  o.x = f2bf(d.x); o.y = f2bf(d.y); o.z = f2bf(d.z); o.w = f2bf(d.w);
  ((ushort4*)dst)[i] = o;
}

// ---------------- NT GEMM: 128x128 tile, 4 waves, REG-STAGED LDS ----------------
// C[M,Nn] = A[M,K] * B[Nn,K]^T, bf16, row strides lA/lB.
// WHY reg-staging: rounds 0-7 showed global_load_lds delivers ~8-10 B/cyc per
// block-stream, saturating ~17 B/cyc/CU regardless of stream count, schedule,
// prefetch depth, or tile size (scores pinned 87-112us, MfmaUtil 26-33% across
// 6 structural variants).  That tracks a per-CU LDS-DMA write-engine rate, not
// L1/L2 BW.  hipBLASLt/HK/AITER all reg-stage (buffer_load->VGPR->ds_write)
// in their peak kernels.  This kernel: plain-C++ loads/stores (no LDS-DMA in
// flight -> no conservative-vmcnt pathology; compiler emits counted waits).
// Per K-tile (BK=64, 2-slot dbuf):
//   ds_write(t)        -- compiler auto-waits ldg(t) (counted vmcnt)
//   __syncthreads()    -- writes visible; drain is empty (ldg(t+1) not issued)
//   ldg(t+1) -> regs   -- 8x global_load_dwordx4, overlaps MFMA below
//   sched_barrier(0)   -- pins the prefetch issue above the MFMA cluster
//   lds reads + 32 MFMA (setprio(1) around cluster)
// Slot safety: reads(t) are lgkm-drained by syncthreads(t+1), which precedes
// dsw(t+2)'s overwrite of slot t&1.  One barrier per tile.
// LDS swizzle (same involution as r7, now applied at ds_write): rows are
// 128 B = 8 granules; source granule g of row r stored at physical g^(r&7);
// read fetches granule (4kk+quad)^(l16&7).  Conflict-free both sides
// (r5/r7: SQ_LDS_BANK_CONFLICT = 0).
// LAUNCH CONVENTION: GX = Nn/128, GY = M/128 (round-6 PV swap fixed).
// EPI: 0 bf16 + bias[col]; 1 bf16 + bias[row]; 2 bf16 exp(val*scale);
//      3 bf16 val/rowsum (ones-MFMA); 4 fp32 + bias[row] + residual X.
// ORD: 0 = bx fastest in g, 1 = by fastest (L2 panel-reuse choice).
template <int EPI, int ORD>
__global__ __launch_bounds__(256, 2) void gemm4(
    const unsigned short* __restrict__ A, long sA, int lA,
    const unsigned short* __restrict__ B, long sB, int lB,
    void* __restrict__ Cp, long sC,
    const float* __restrict__ bias,
    const float* __restrict__ X, long sX,
    int GX, int GY, int Nn, int K) {
  constexpr int BM = 128, BN = 128;
  constexpr int TM = 4, TN = 4;

  __shared__ __align__(16) unsigned short As[2 * BM * 64];   // 32 KB
  __shared__ __align__(16) unsigned short Bs[2 * BN * 64];   // 32 KB

  const int tid = threadIdx.x;
  const int nwg = gridDim.x;
  // bijective XCD-chunk mapping (nwg % 8 == 0 for all launches)
  const int g = (blockIdx.x & 7) * (nwg >> 3) + (blockIdx.x >> 3);
  int bx, by, bz;
  if (ORD == 0) { bx = g % GX; int t = g / GX; by = t % GY; bz = t / GY; }
  else          { by = g % GY; int t = g / GY; bx = t % GX; bz = t / GX; }

  A += (long)bz * sA;
  B += (long)bz * sB;
  const int m0 = by * BM;
  const int n0 = bx * BN;
  const int lane = tid & 63;
  const int wv = tid >> 6;             // 0..3, wave grid 2x2
  const int wm = (wv >> 1) * 64;
  const int wn = (wv & 1) * 64;
  const int l16 = lane & 15;
  const int quad = lane >> 4;
  const int sw7 = l16 & 7;
  const int rg0 = ((0 + quad) ^ sw7) << 3;   // kk=0 swizzled granule, elems
  const int rg1 = ((4 + quad) ^ sw7) << 3;   // kk=1

  // reg-staging map: 256 thr x (4 A + 4 B) x 16 B; load i covers rows i*32..+31
  const int r0s  = wv * 8 + (lane >> 3);              // 0..31
  const int gcol = (lane & 7) << 3;                   // source granule, elems
  const unsigned short* Ag = A + (long)(m0 + r0s) * lA + gcol;
  const unsigned short* Bg = B + (long)(n0 + r0s) * lB + gcol;
  // ds_write byte offset in slot: row*128 + (g ^ (row&7))*16; row&7 == lane>>3
  const int wrofs = r0s * 128 + ((((lane & 7) ^ (lane >> 3)) & 7) << 4);

  const int nt = K >> 6;

  uint4 rA[4], rB[4];
  auto ldg = [&](int t) {
    if (t < nt) {
      const int k0 = t << 6;
#pragma unroll
      for (int i = 0; i < 4; ++i) {
        rA[i] = *(const uint4*)(Ag + (long)i * 32 * lA + k0);
        rB[i] = *(const uint4*)(Bg + (long)i * 32 * lB + k0);
      }
    }
  };
  auto dsw = [&](int t) {
    char* Ad = (char*)As + (t & 1) * 16384;
    char* Bd = (char*)Bs + (t & 1) * 16384;
#pragma unroll
    for (int i = 0; i < 4; ++i) {
      *(uint4*)(Ad + i * 4096 + wrofs) = rA[i];
      *(uint4*)(Bd + i * 4096 + wrofs) = rB[i];
    }
  };

  f4v acc[TM][TN] = {};
  f4v accr[TM] = {};                   // EPI==3 row-sums (DCE'd otherwise)
  bf8v ones;
#pragma unroll
  for (int i = 0; i < 8; ++i) ones[i] = (__bf16)1.0f;

  ldg(0);
  for (int t = 0; t < nt; ++t) {
    dsw(t);
    __syncthreads();
    ldg(t + 1);
    __builtin_amdgcn_sched_barrier(0);
    const unsigned short* Ab = As + (t & 1) * (BM * 64);
    const unsigned short* Bb = Bs + (t & 1) * (BN * 64);
    bf8v bfr[TN][2], afr[TM][2];
#pragma unroll
    for (int tn = 0; tn < TN; ++tn) {
      bfr[tn][0] = *(const bf8v*)&Bb[(wn + tn * 16 + l16) * 64 + rg0];
      bfr[tn][1] = *(const bf8v*)&Bb[(wn + tn * 16 + l16) * 64 + rg1];
    }
#pragma unroll
    for (int tm = 0; tm < TM; ++tm) {
      afr[tm][0] = *(const bf8v*)&Ab[(wm + tm * 16 + l16) * 64 + rg0];
      afr[tm][1] = *(const bf8v*)&Ab[(wm + tm * 16 + l16) * 64 + rg1];
    }
    __builtin_amdgcn_s_setprio(1);
#pragma unroll
    for (int kk = 0; kk < 2; ++kk)
#pragma unroll
      for (int tm = 0; tm < TM; ++tm) {
#pragma unroll
        for (int tn = 0; tn < TN; ++tn)
          acc[tm][tn] = __builtin_amdgcn_mfma_f32_16x16x32_bf16(
              afr[tm][kk], bfr[tn][kk], acc[tm][tn], 0, 0, 0);
        if (EPI == 3)
          accr[tm] = __builtin_amdgcn_mfma_f32_16x16x32_bf16(
              afr[tm][kk], ones, accr[tm], 0, 0, 0);
      }
    __builtin_amdgcn_s_setprio(0);
  }

  // C/D layout (verified m89/m91): col = lane&15, row = quad*4 + reg
  if (EPI == 2) {
#pragma unroll
    for (int tm = 0; tm < TM; ++tm) {
#pragma unroll
      for (int r = 0; r < 4; ++r) {
        const int row = m0 + wm + tm * 16 + quad * 4 + r;
#pragma unroll
        for (int tn = 0; tn < TN; ++tn) {
          const int col = n0 + wn + tn * 16 + l16;
          float e = __expf(acc[tm][tn][r] * 0.044194173824159216f);
          ((unsigned short*)Cp)[(long)bz * sC + (long)row * Nn + col] = f2bf(e);
        }
      }
    }
  } else if (EPI == 3) {
#pragma unroll
    for (int tm = 0; tm < TM; ++tm) {
#pragma unroll
      for (int r = 0; r < 4; ++r) {
        const int row = m0 + wm + tm * 16 + quad * 4 + r;
        const float inv = 1.0f / accr[tm][r];
#pragma unroll
        for (int tn = 0; tn < TN; ++tn) {
          const int col = n0 + wn + tn * 16 + l16;
          ((unsigned short*)Cp)[(long)bz * sC + (long)row * Nn + col] =
              f2bf(acc[tm][tn][r] * inv);
        }
      }
    }
  } else {
#pragma unroll
    for (int tm = 0; tm < TM; ++tm) {
#pragma unroll
      for (int tn = 0; tn < TN; ++tn) {
        const int col = n0 + wn + tn * 16 + l16;
#pragma unroll
        for (int r = 0; r < 4; ++r) {
          const int row = m0 + wm + tm * 16 + quad * 4 + r;
          float val = acc[tm][tn][r];
          if (EPI == 0) {
            val += bias[col];
            ((unsigned short*)Cp)[(long)bz * sC + (long)row * Nn + col] = f2bf(val);
          } else if (EPI == 1) {
            val += bias[row];
            ((unsigned short*)Cp)[(long)bz * sC + (long)row * Nn + col] = f2bf(val);
          } else {
            ((float*)Cp)[(long)bz * sC + (long)row * Nn + col] =
                val + bias[row] + X[(long)bz * sX + (long)row * Nn + col];
          }
        }
      }
    }
  }
}

extern "C" void kernel_launch(void* const* d_in, const int* in_sizes, int n_in,
                              void* d_out, int out_size, void* d_ws, size_t ws_size,
                              hipStream_t stream) {
  (void)in_sizes; (void)n_in; (void)out_size;
  const float* x  = (const float*)d_in[0];
  const float* gs = (const float*)d_in[1];
  const float* gb = (const float*)d_in[2];
  const float* wq = (const float*)d_in[3];
  const float* bq = (const float*)d_in[4];
  const float* wk = (const float*)d_in[5];
  const float* bk = (const float*)d_in[6];
  const float* wv = (const float*)d_in[7];
  const float* bv = (const float*)d_in[8];
  const float* wp = (const float*)d_in[9];
  const float* bp = (const float*)d_in[10];
  float* out = (float*)d_out;

  char* ws = (char*)d_ws;
  const long NC  = (long)NDIM * CDIM;        // per-batch [N,C] elems
  const long NQK = (long)NDIM * 1024;        // per-batch [N,1024] elems
  const long BUF = NC * 2 * BATCH;           // [B,N,C] bf16 buffer = 16,777,216 B
  const long NN  = (long)NDIM * NDIM;

  // Layout (aliased):
  //   [0, BUF)        hT, later OT
  //   [BUF, 3BUF)     qkT [B,N,1024]; later wpb overlays its head
  //   [3BUF, 4BUF)    vB [B,C,N]
  //   [4BUF, ...)     sc: bf16 unnormalized exp-scores P'; head doubles as
  //                   wqkb/wvb/bqk/stats (all dead before scores GEMM writes)
  unsigned short* hT   = (unsigned short*)(ws);
  unsigned short* OT   = hT;
  unsigned short* qkT  = (unsigned short*)(ws + BUF);
  unsigned short* vB   = (unsigned short*)(ws + BUF * 3);
  unsigned short* sc   = (unsigned short*)(ws + BUF * 4);
  unsigned short* wqkb = sc;                                   // 1 MB
  unsigned short* wvb  = (unsigned short*)(ws + BUF * 4 + 1048576);
  float* bqk           = (float*)(ws + BUF * 4 + 1572864);
  float* stats         = (float*)(ws + BUF * 4 + 1581056);
  unsigned short* wpb  = qkT;  // overlays dead qkT for final proj

  gn_stats_kernel<<<BATCH * 32, 256, 0, stream>>>(x, stats);
  gn_transpose_kernel<<<dim3(NDIM / 64, CDIM / 64, BATCH), 256, 0, stream>>>(x, gs, gb, stats, hT);
  prep_kernel<<<769, 256, 0, stream>>>(wq, wk, wv, bq, bk, wqkb, wvb, bqk);

  // qkT = hT * [wq;wk]^T + bqk  ([N,1024]) : GX=1024/128=8, GY=4096/128=32
  gemm4<0, 0><<<1024, 256, 0, stream>>>(
      hT, NC, CDIM, wqkb, 0, CDIM, qkT, NQK, bqk, nullptr, 0, 8, 32, 1024, CDIM);
  // v = wv * hT^T + bv  ([C,N]) : GX=4096/128=32, GY=512/128=4
  gemm4<1, 1><<<512, 256, 0, stream>>>(
      wvb, 0, CDIM, hT, NC, CDIM, vB, NC, bv, nullptr, 0, 32, 4, NDIM, CDIM);

  if (ws_size >= (size_t)(BUF * 4) + (size_t)(NN * 2) * BATCH) {
    // Primary (192 MiB): fully batched attention, softmax fused away.
    gemm4<2, 0><<<4096, 256, 0, stream>>>(
        qkT, NQK, 1024, qkT + 512, NQK, 1024, sc, NN, nullptr, nullptr, 0,
        32, 32, NDIM, CDIM);
    // PV: OT[M=4096, Nn=512] -> GX=512/128=4, GY=4096/128=32
    gemm4<3, 1><<<512, 256, 0, stream>>>(
        sc, NN, NDIM, vB, NC, NDIM, OT, NC, nullptr, nullptr, 0,
        4, 32, CDIM, NDIM);
  } else {
    // Fallback (~101 MB): per-batch rounds.
    for (int b = 0; b < BATCH; ++b) {
      gemm4<2, 0><<<1024, 256, 0, stream>>>(
          qkT + b * NQK, 0, 1024, qkT + b * NQK + 512, 0, 1024, sc, 0,
          nullptr, nullptr, 0, 32, 32, NDIM, CDIM);
      gemm4<3, 1><<<128, 256, 0, stream>>>(
          sc, 0, NDIM, vB + b * NC, 0, NDIM, OT + b * NC, 0,
          nullptr, nullptr, 0, 4, 32, CDIM, NDIM);
    }
  }

  // out = wp * OT^T + bp + x  (fp32 out, fused residual); wpb overlays dead qkT
  cvt_kernel<<<256, 256, 0, stream>>>(wp, wpb, 65536);
  gemm4<4, 1><<<512, 256, 0, stream>>>(
      wpb, 0, CDIM, OT, NC, CDIM, out, NC, bp, x, NC, 32, 4, NDIM, CDIM);
}

// Round 9
// 339.209 us; speedup vs baseline: 2.1198x; 2.1198x over previous
//
#include <hip/hip_runtime.h>

#define CDIM 512
#define NDIM 4096
#define BATCH 4

using bf8v = __attribute__((ext_vector_type(8))) __bf16;
using f4v  = __attribute__((ext_vector_type(4))) float;

typedef __attribute__((address_space(1))) unsigned int gu32;
typedef __attribute__((address_space(3))) unsigned int lu32;

static __device__ __forceinline__ unsigned short f2bf(float f) {
  unsigned int u = __float_as_uint(f);
  u += 0x7fffu + ((u >> 16) & 1u);   // round-to-nearest-even
  return (unsigned short)(u >> 16);
}

// inline-asm LDS read: invisible to SIInsertWaitcnts' LDS-DMA tracking, so no
// conservative vmcnt(0) is inserted while global_load_lds prefetches are in
// flight.  Data validity is guaranteed by the explicit vmcnt/barrier/lgkmcnt
// protocol in the K-loop.
static __device__ __forceinline__ bf8v lds_read16(const unsigned short* p) {
  bf8v r;
  unsigned off = (unsigned)(unsigned long long)p;
  asm volatile("ds_read_b128 %0, %1" : "=v"(r) : "v"(off));
  return r;
}

// ---------------- GN pass 1: per-(b,g) mean/rstd ----------------
__global__ __launch_bounds__(256) void gn_stats_kernel(
    const float* __restrict__ x, float* __restrict__ stats) {
  const int tid = threadIdx.x;
  const float4* xv = (const float4*)(x + (long)blockIdx.x * 65536);
  float s = 0.f, ss = 0.f;
  for (int i = tid; i < 16384; i += 256) {
    float4 d = xv[i];
    s  += d.x + d.y + d.z + d.w;
    ss += d.x * d.x + d.y * d.y + d.z * d.z + d.w * d.w;
  }
#pragma unroll
  for (int off = 32; off; off >>= 1) {
    s  += __shfl_down(s, off);
    ss += __shfl_down(ss, off);
  }
  __shared__ float red[8];
  if ((tid & 63) == 0) { red[tid >> 6] = s; red[4 + (tid >> 6)] = ss; }
  __syncthreads();
  if (tid == 0) {
    float S  = red[0] + red[1] + red[2] + red[3];
    float SS = red[4] + red[5] + red[6] + red[7];
    float mean = S * (1.f / 65536.f);
    float var  = SS * (1.f / 65536.f) - mean * mean;
    stats[blockIdx.x * 2]     = mean;
    stats[blockIdx.x * 2 + 1] = rsqrtf(var + 1e-6f);
  }
}

// ---------------- GN pass 2: normalize + transpose, fp32 [C,N] -> bf16 [N,C] ----------------
__global__ __launch_bounds__(256) void gn_transpose_kernel(
    const float* __restrict__ x, const float* __restrict__ gs,
    const float* __restrict__ gb, const float* __restrict__ stats,
    unsigned short* __restrict__ hT) {
  __shared__ float t[64][65];
  const int tid = threadIdx.x;
  const int b = blockIdx.z;
  const long bbx = (long)b * ((long)CDIM * NDIM);
  const int n0 = blockIdx.x * 64, c0 = blockIdx.y * 64;
  for (int k = 0; k < 4; ++k) {
    int it = tid + k * 256;
    int c = it >> 4, no = (it & 15) << 2;
    int ch = c0 + c;
    int g = ch >> 4;
    float mean = stats[(b * 32 + g) * 2];
    float rstd = stats[(b * 32 + g) * 2 + 1];
    float a  = rstd * gs[ch];
    float bb = gb[ch] - mean * a;
    float4 d = *(const float4*)&x[bbx + (long)ch * NDIM + n0 + no];
    t[no + 0][c] = d.x * a + bb;
    t[no + 1][c] = d.y * a + bb;
    t[no + 2][c] = d.z * a + bb;
    t[no + 3][c] = d.w * a + bb;
  }
  __syncthreads();
  const long bbh = (long)b * ((long)NDIM * CDIM);
  for (int k = 0; k < 2; ++k) {
    int it = tid + k * 256;
    int n = it >> 3, co = (it & 7) << 3;
    unsigned int ow[4];
#pragma unroll
    for (int j = 0; j < 4; ++j) {
      unsigned short lo = f2bf(t[n][co + 2 * j]);
      unsigned short hi = f2bf(t[n][co + 2 * j + 1]);
      ow[j] = (unsigned int)lo | ((unsigned int)hi << 16);
    }
    uint4 o; o.x = ow[0]; o.y = ow[1]; o.z = ow[2]; o.w = ow[3];
    *(uint4*)&hT[bbh + (long)(n0 + n) * CDIM + c0 + co] = o;
  }
}

// ---------------- merged prep: wq/wk/wv fp32->bf16 + bias concat ----------------
__global__ __launch_bounds__(256) void prep_kernel(
    const float* __restrict__ wq, const float* __restrict__ wk,
    const float* __restrict__ wv, const float* __restrict__ bq,
    const float* __restrict__ bk, unsigned short* __restrict__ wqkb,
    unsigned short* __restrict__ wvb, float* __restrict__ bqk) {
  int blk = blockIdx.x;
  if (blk < 768) {
    int i = blk * 256 + threadIdx.x;
    const float* src = (blk < 256) ? wq : (blk < 512) ? wk : wv;
    unsigned short* dst = (blk < 256) ? wqkb : (blk < 512) ? (wqkb + 262144) : wvb;
    int j = i - ((blk < 256) ? 0 : (blk < 512) ? 65536 : 131072);
    float4 d = ((const float4*)src)[j];
    ushort4 o;
    o.x = f2bf(d.x); o.y = f2bf(d.y); o.z = f2bf(d.z); o.w = f2bf(d.w);
    ((ushort4*)dst)[j] = o;
  } else {
#pragma unroll
    for (int k = 0; k < 4; ++k) {
      int i = threadIdx.x + k * 256;
      bqk[i] = (i < 512) ? bq[i] : bk[i - 512];
    }
  }
}

// ---------------- fp32 -> bf16 convert (wp, launched late) ----------------
__global__ __launch_bounds__(256) void cvt_kernel(
    const float* __restrict__ src, unsigned short* __restrict__ dst, int n4) {
  int i = blockIdx.x * 256 + threadIdx.x;
  if (i >= n4) return;
  float4 d = ((const float4*)src)[i];
  ushort4 o;
  o.x = f2bf(d.x); o.y = f2bf(d.y); o.z = f2bf(d.z); o.w = f2bf(d.w);
  ((ushort4*)dst)[i] = o;
}

// ======================= MODEL (rounds 0-8) =======================
// Staging via global_load_lds is the binding resource: chip-wide it tops out
// ~10.5 TB/s (~17-18 B/cyc/CU) and ONLY with >=2 concurrent block-streams per
// CU (single stream stop-and-goes at ~9-10 B/cyc).  Reg-staging (r8) is far
// worse (conflicts+spills, MfmaUtil 12%).  Perf = min(MFMA peak,
// intensity[FLOP/staged-byte] x staging-rate).  128^2 tile = 64 F/B -> ~30%
// (r7 measured).  2 blocks/CU requires <=128 VGPR (acc/thread = BM*BN/thr
// <= 64) and <=80 KB LDS; the max-intensity feasible point is 256x128/BK32
// (87 F/B) -> gemm8n below, used where the grid gives >=512 blocks.
// ==================================================================

// ---------------- gemm4: 128x128, BK=64, 4 waves, 2 blocks/CU (r7, proven) ----------------
// EPI: 0 bf16 + bias[col]; 1 bf16 + bias[row]; 2 bf16 exp(val*scale);
//      3 bf16 val/rowsum (ones-MFMA); 4 fp32 + bias[row] + residual X.
// ORD: 0 = bx fastest in g, 1 = by fastest.  GX = Nn/BN, GY = M/BM.
template <int EPI, int ORD>
__global__ __launch_bounds__(256, 2) void gemm4(
    const unsigned short* __restrict__ A, long sA, int lA,
    const unsigned short* __restrict__ B, long sB, int lB,
    void* __restrict__ Cp, long sC,
    const float* __restrict__ bias,
    const float* __restrict__ X, long sX,
    int GX, int GY, int Nn, int K) {
  constexpr int BM = 128, BN = 128;
  constexpr int TM = 4, TN = 4;
  constexpr int LA = 4, LB = 4;

  __shared__ __align__(16) unsigned short As[2 * BM * 64];   // 32 KB
  __shared__ __align__(16) unsigned short Bs[2 * BN * 64];   // 32 KB

  const int tid = threadIdx.x;
  const int nwg = gridDim.x;
  const int g = (blockIdx.x & 7) * (nwg >> 3) + (blockIdx.x >> 3);
  int bx, by, bz;
  if (ORD == 0) { bx = g % GX; int t = g / GX; by = t % GY; bz = t / GY; }
  else          { by = g % GY; int t = g / GY; bx = t % GX; bz = t / GX; }

  A += (long)bz * sA;
  B += (long)bz * sB;
  const int m0 = by * BM;
  const int n0 = bx * BN;
  const int lane = tid & 63;
  const int wv = tid >> 6;             // 0..3, wave grid 2x2
  const int wm = (wv >> 1) * 64;
  const int wn = (wv & 1) * 64;
  const int l16 = lane & 15;
  const int quad = lane >> 4;
  const int sw7 = l16 & 7;
  const int rg0 = ((0 + quad) ^ sw7) << 3;   // 128-B rows: key = row&7
  const int rg1 = ((4 + quad) ^ sw7) << 3;

  const int r0s  = wv * 8 + (lane >> 3);              // 0..31
  const int gsrc = ((lane & 7) ^ (lane >> 3)) << 3;   // pre-swizzled source
  const unsigned short* Ag = A + (long)(m0 + r0s) * lA + gsrc;
  const unsigned short* Bg = B + (long)(n0 + r0s) * lB + gsrc;

  const int nt = K >> 6;

  auto stage = [&](int t) {
    if (t < nt) {
      const int k0 = t << 6;
      unsigned short* Ad = As + (t & 1) * (BM * 64) + wv * 512;
      unsigned short* Bd = Bs + (t & 1) * (BN * 64) + wv * 512;
#pragma unroll
      for (int i = 0; i < LA; ++i)
        __builtin_amdgcn_global_load_lds(
            (const gu32*)(Ag + (long)i * 32 * lA + k0),
            (lu32*)(Ad + i * 2048), 16, 0, 0);
#pragma unroll
      for (int i = 0; i < LB; ++i)
        __builtin_amdgcn_global_load_lds(
            (const gu32*)(Bg + (long)i * 32 * lB + k0),
            (lu32*)(Bd + i * 2048), 16, 0, 0);
    }
  };

  f4v acc[TM][TN] = {};
  f4v accr[TM] = {};
  bf8v ones;
#pragma unroll
  for (int i = 0; i < 8; ++i) ones[i] = (__bf16)1.0f;

  bf8v bfr[TN][2];
  bf8v afA[2][2], afB[2][2];

  const unsigned short* Ab;
  const unsigned short* Bb;

  auto rdB = [&]() {
#pragma unroll
    for (int tn = 0; tn < TN; ++tn) {
      bfr[tn][0] = lds_read16(&Bb[(wn + tn * 16 + l16) * 64 + rg0]);
      bfr[tn][1] = lds_read16(&Bb[(wn + tn * 16 + l16) * 64 + rg1]);
    }
  };
  auto rdA = [&](int q, bf8v (&fr)[2][2]) {
#pragma unroll
    for (int dr = 0; dr < 2; ++dr) {
      fr[dr][0] = lds_read16(&Ab[(wm + (q * 2 + dr) * 16 + l16) * 64 + rg0]);
      fr[dr][1] = lds_read16(&Ab[(wm + (q * 2 + dr) * 16 + l16) * 64 + rg1]);
    }
  };
  auto clus = [&](int q, bf8v (&fr)[2][2]) {
    __builtin_amdgcn_s_setprio(1);
#pragma unroll
    for (int kk = 0; kk < 2; ++kk)
#pragma unroll
      for (int dr = 0; dr < 2; ++dr) {
        const int tm = q * 2 + dr;
#pragma unroll
        for (int tn = 0; tn < TN; ++tn)
          acc[tm][tn] = __builtin_amdgcn_mfma_f32_16x16x32_bf16(
              fr[dr][kk], bfr[tn][kk], acc[tm][tn], 0, 0, 0);
        if (EPI == 3)
          accr[tm] = __builtin_amdgcn_mfma_f32_16x16x32_bf16(
              fr[dr][kk], ones, accr[tm], 0, 0, 0);
      }
    __builtin_amdgcn_s_setprio(0);
  };

  stage(0);
  for (int t = 0; t < nt; ++t) {
    asm volatile("s_waitcnt vmcnt(0)");          // stage(t): issued 1 tile ago
    __builtin_amdgcn_s_barrier();
    stage(t + 1);
    Ab = As + (t & 1) * (BM * 64);
    Bb = Bs + (t & 1) * (BN * 64);
    rdB();
    rdA(0, afA);
    rdA(1, afB);
    asm volatile("s_waitcnt lgkmcnt(4)");
    __builtin_amdgcn_sched_barrier(0);
    clus(0, afA);
    asm volatile("s_waitcnt lgkmcnt(0)");
    __builtin_amdgcn_sched_barrier(0);
    clus(1, afB);
  }

  // C/D layout (verified m89/m91): col = lane&15, row = quad*4 + reg
  if (EPI == 2) {
#pragma unroll
    for (int tm = 0; tm < TM; ++tm) {
#pragma unroll
      for (int r = 0; r < 4; ++r) {
        const int row = m0 + wm + tm * 16 + quad * 4 + r;
#pragma unroll
        for (int tn = 0; tn < TN; ++tn) {
          const int col = n0 + wn + tn * 16 + l16;
          float e = __expf(acc[tm][tn][r] * 0.044194173824159216f);
          ((unsigned short*)Cp)[(long)bz * sC + (long)row * Nn + col] = f2bf(e);
        }
      }
    }
  } else if (EPI == 3) {
#pragma unroll
    for (int tm = 0; tm < TM; ++tm) {
#pragma unroll
      for (int r = 0; r < 4; ++r) {
        const int row = m0 + wm + tm * 16 + quad * 4 + r;
        const float inv = 1.0f / accr[tm][r];
#pragma unroll
        for (int tn = 0; tn < TN; ++tn) {
          const int col = n0 + wn + tn * 16 + l16;
          ((unsigned short*)Cp)[(long)bz * sC + (long)row * Nn + col] =
              f2bf(acc[tm][tn][r] * inv);
        }
      }
    }
  } else {
#pragma unroll
    for (int tm = 0; tm < TM; ++tm) {
#pragma unroll
      for (int tn = 0; tn < TN; ++tn) {
        const int col = n0 + wn + tn * 16 + l16;
#pragma unroll
        for (int r = 0; r < 4; ++r) {
          const int row = m0 + wm + tm * 16 + quad * 4 + r;
          float val = acc[tm][tn][r];
          if (EPI == 0) {
            val += bias[col];
            ((unsigned short*)Cp)[(long)bz * sC + (long)row * Nn + col] = f2bf(val);
          } else if (EPI == 1) {
            val += bias[row];
            ((unsigned short*)Cp)[(long)bz * sC + (long)row * Nn + col] = f2bf(val);
          } else {
            ((float*)Cp)[(long)bz * sC + (long)row * Nn + col] =
                val + bias[row] + X[(long)bz * sX + (long)row * Nn + col];
          }
        }
      }
    }
  }
}

// ---------------- gemm8n: 256x128, BK=32, 8 waves, 2 blocks/CU ----------------
// Higher intensity (87 F/B vs 64) at the same 2-stream occupancy: acc = 64
// VGPR/thread (64x64 per wave, wave grid 4Mx2N), 48 KB LDS, launch_bounds
// (512,4) pins <=128 VGPR.  BK=32 -> 64-B LDS rows -> swizzle key (row>>1)&3
// (r2-derived, measured 0 conflicts) on both gload source and read.
// Same sequential K order as gemm4 -> bit-identical accumulation.
template <int EPI, int ORD>
__global__ __launch_bounds__(512, 4) void gemm8n(
    const unsigned short* __restrict__ A, long sA, int lA,
    const unsigned short* __restrict__ B, long sB, int lB,
    void* __restrict__ Cp, long sC,
    const float* __restrict__ bias,
    const float* __restrict__ X, long sX,
    int GX, int GY, int Nn, int K) {
  constexpr int BM = 256, BN = 128;
  constexpr int TM = 4, TN = 4;

  __shared__ __align__(16) unsigned short As[2 * BM * 32];   // 32 KB
  __shared__ __align__(16) unsigned short Bs[2 * BN * 32];   // 16 KB

  const int tid = threadIdx.x;
  const int nwg = gridDim.x;
  const int g = (blockIdx.x & 7) * (nwg >> 3) + (blockIdx.x >> 3);
  int bx, by, bz;
  if (ORD == 0) { bx = g % GX; int t = g / GX; by = t % GY; bz = t / GY; }
  else          { by = g % GY; int t = g / GY; bx = t % GX; bz = t / GX; }

  A += (long)bz * sA;
  B += (long)bz * sB;
  const int m0 = by * BM;
  const int n0 = bx * BN;
  const int lane = tid & 63;
  const int wv = tid >> 6;             // 0..7, wave grid 4(M) x 2(N)
  const int wm = (wv >> 1) * 64;
  const int wn = (wv & 1) * 64;
  const int l16 = lane & 15;
  const int quad = lane >> 4;
  const int rg = (quad ^ ((l16 >> 1) & 3)) << 3;   // 64-B rows: key=(row>>1)&3

  // staging: per gload 512 thr x 16 B = 8 KB = 128 rows x 4 granules
  const int rl = tid >> 2;             // 0..127
  const int gl = tid & 3;
  const int gsrc = (gl ^ ((rl >> 1) & 3)) << 3;     // pre-swizzled source
  const unsigned short* Ag = A + (long)(m0 + rl) * lA + gsrc;
  const unsigned short* Bg = B + (long)(n0 + rl) * lB + gsrc;

  const int nt = K >> 5;

  auto stage = [&](int t) {
    if (t < nt) {
      const int k0 = t << 5;
      unsigned short* Ad = As + (t & 1) * (BM * 32) + wv * 512;
      unsigned short* Bd = Bs + (t & 1) * (BN * 32) + wv * 512;
      __builtin_amdgcn_global_load_lds((const gu32*)(Ag + k0),
                                       (lu32*)(Ad), 16, 0, 0);
      __builtin_amdgcn_global_load_lds((const gu32*)(Ag + (long)128 * lA + k0),
                                       (lu32*)(Ad + 4096), 16, 0, 0);
      __builtin_amdgcn_global_load_lds((const gu32*)(Bg + k0),
                                       (lu32*)(Bd), 16, 0, 0);
    }
  };

  f4v acc[TM][TN] = {};
  f4v accr[TM] = {};
  bf8v ones;
#pragma unroll
  for (int i = 0; i < 8; ++i) ones[i] = (__bf16)1.0f;

  stage(0);
  for (int t = 0; t < nt; ++t) {
    asm volatile("s_waitcnt vmcnt(0)");          // stage(t): issued 1 tile ago
    __builtin_amdgcn_s_barrier();
    stage(t + 1);
    const unsigned short* Ab = As + (t & 1) * (BM * 32);
    const unsigned short* Bb = Bs + (t & 1) * (BN * 32);
    bf8v af[TM], bf[TN];
#pragma unroll
    for (int tn = 0; tn < TN; ++tn)
      bf[tn] = lds_read16(&Bb[(wn + tn * 16 + l16) * 32 + rg]);
#pragma unroll
    for (int tm = 0; tm < TM; ++tm)
      af[tm] = lds_read16(&Ab[(wm + tm * 16 + l16) * 32 + rg]);
    asm volatile("s_waitcnt lgkmcnt(2)");        // bf0-3 + af0,af1 done
    __builtin_amdgcn_sched_barrier(0);
    __builtin_amdgcn_s_setprio(1);
#pragma unroll
    for (int tm = 0; tm < 2; ++tm) {
#pragma unroll
      for (int tn = 0; tn < TN; ++tn)
        acc[tm][tn] = __builtin_amdgcn_mfma_f32_16x16x32_bf16(
            af[tm], bf[tn], acc[tm][tn], 0, 0, 0);
      if (EPI == 3)
        accr[tm] = __builtin_amdgcn_mfma_f32_16x16x32_bf16(
            af[tm], ones, accr[tm], 0, 0, 0);
    }
    __builtin_amdgcn_s_setprio(0);
    asm volatile("s_waitcnt lgkmcnt(0)");        // af2,af3 done
    __builtin_amdgcn_sched_barrier(0);
    __builtin_amdgcn_s_setprio(1);
#pragma unroll
    for (int tm = 2; tm < TM; ++tm) {
#pragma unroll
      for (int tn = 0; tn < TN; ++tn)
        acc[tm][tn] = __builtin_amdgcn_mfma_f32_16x16x32_bf16(
            af[tm], bf[tn], acc[tm][tn], 0, 0, 0);
      if (EPI == 3)
        accr[tm] = __builtin_amdgcn_mfma_f32_16x16x32_bf16(
            af[tm], ones, accr[tm], 0, 0, 0);
    }
    __builtin_amdgcn_s_setprio(0);
  }

  // C/D layout (verified m89/m91): col = lane&15, row = quad*4 + reg
  if (EPI == 2) {
#pragma unroll
    for (int tm = 0; tm < TM; ++tm) {
#pragma unroll
      for (int r = 0; r < 4; ++r) {
        const int row = m0 + wm + tm * 16 + quad * 4 + r;
#pragma unroll
        for (int tn = 0; tn < TN; ++tn) {
          const int col = n0 + wn + tn * 16 + l16;
          float e = __expf(acc[tm][tn][r] * 0.044194173824159216f);
          ((unsigned short*)Cp)[(long)bz * sC + (long)row * Nn + col] = f2bf(e);
        }
      }
    }
  } else if (EPI == 3) {
#pragma unroll
    for (int tm = 0; tm < TM; ++tm) {
#pragma unroll
      for (int r = 0; r < 4; ++r) {
        const int row = m0 + wm + tm * 16 + quad * 4 + r;
        const float inv = 1.0f / accr[tm][r];
#pragma unroll
        for (int tn = 0; tn < TN; ++tn) {
          const int col = n0 + wn + tn * 16 + l16;
          ((unsigned short*)Cp)[(long)bz * sC + (long)row * Nn + col] =
              f2bf(acc[tm][tn][r] * inv);
        }
      }
    }
  } else {
#pragma unroll
    for (int tm = 0; tm < TM; ++tm) {
#pragma unroll
      for (int tn = 0; tn < TN; ++tn) {
        const int col = n0 + wn + tn * 16 + l16;
#pragma unroll
        for (int r = 0; r < 4; ++r) {
          const int row = m0 + wm + tm * 16 + quad * 4 + r;
          float val = acc[tm][tn][r];
          if (EPI == 0) {
            val += bias[col];
            ((unsigned short*)Cp)[(long)bz * sC + (long)row * Nn + col] = f2bf(val);
          } else if (EPI == 1) {
            val += bias[row];
            ((unsigned short*)Cp)[(long)bz * sC + (long)row * Nn + col] = f2bf(val);
          } else {
            ((float*)Cp)[(long)bz * sC + (long)row * Nn + col] =
                val + bias[row] + X[(long)bz * sX + (long)row * Nn + col];
          }
        }
      }
    }
  }
}

extern "C" void kernel_launch(void* const* d_in, const int* in_sizes, int n_in,
                              void* d_out, int out_size, void* d_ws, size_t ws_size,
                              hipStream_t stream) {
  (void)in_sizes; (void)n_in; (void)out_size;
  const float* x  = (const float*)d_in[0];
  const float* gs = (const float*)d_in[1];
  const float* gb = (const float*)d_in[2];
  const float* wq = (const float*)d_in[3];
  const float* bq = (const float*)d_in[4];
  const float* wk = (const float*)d_in[5];
  const float* bk = (const float*)d_in[6];
  const float* wv = (const float*)d_in[7];
  const float* bv = (const float*)d_in[8];
  const float* wp = (const float*)d_in[9];
  const float* bp = (const float*)d_in[10];
  float* out = (float*)d_out;

  char* ws = (char*)d_ws;
  const long NC  = (long)NDIM * CDIM;        // per-batch [N,C] elems
  const long NQK = (long)NDIM * 1024;        // per-batch [N,1024] elems
  const long BUF = NC * 2 * BATCH;           // [B,N,C] bf16 buffer = 16,777,216 B
  const long NN  = (long)NDIM * NDIM;

  // Layout (aliased):
  //   [0, BUF)        hT, later OT
  //   [BUF, 3BUF)     qkT [B,N,1024]; later wpb overlays its head
  //   [3BUF, 4BUF)    vB [B,C,N]
  //   [4BUF, ...)     sc: bf16 unnormalized exp-scores P'; head doubles as
  //                   wqkb/wvb/bqk/stats (all dead before scores GEMM writes)
  unsigned short* hT   = (unsigned short*)(ws);
  unsigned short* OT   = hT;
  unsigned short* qkT  = (unsigned short*)(ws + BUF);
  unsigned short* vB   = (unsigned short*)(ws + BUF * 3);
  unsigned short* sc   = (unsigned short*)(ws + BUF * 4);
  unsigned short* wqkb = sc;                                   // 1 MB
  unsigned short* wvb  = (unsigned short*)(ws + BUF * 4 + 1048576);
  float* bqk           = (float*)(ws + BUF * 4 + 1572864);
  float* stats         = (float*)(ws + BUF * 4 + 1581056);
  unsigned short* wpb  = qkT;  // overlays dead qkT for final proj

  gn_stats_kernel<<<BATCH * 32, 256, 0, stream>>>(x, stats);
  gn_transpose_kernel<<<dim3(NDIM / 64, CDIM / 64, BATCH), 256, 0, stream>>>(x, gs, gb, stats, hT);
  prep_kernel<<<769, 256, 0, stream>>>(wq, wk, wv, bq, bk, wqkb, wvb, bqk);

  // qkT = hT * [wq;wk]^T + bqk  ([N,1024]) : 256x128 tiles, GX=8, GY=16
  gemm8n<0, 0><<<512, 512, 0, stream>>>(
      hT, NC, CDIM, wqkb, 0, CDIM, qkT, NQK, bqk, nullptr, 0, 8, 16, 1024, CDIM);
  // v = wv * hT^T + bv  ([C,N]) : 128x128, GX=32, GY=4
  gemm4<1, 1><<<512, 256, 0, stream>>>(
      wvb, 0, CDIM, hT, NC, CDIM, vB, NC, bv, nullptr, 0, 32, 4, NDIM, CDIM);

  if (ws_size >= (size_t)(BUF * 4) + (size_t)(NN * 2) * BATCH) {
    // Primary (192 MiB): fully batched attention, softmax fused away.
    // scores: 256x128 tiles, GX=4096/128=32, GY=4096/256=16 -> 2048 blocks
    gemm8n<2, 0><<<2048, 512, 0, stream>>>(
        qkT, NQK, 1024, qkT + 512, NQK, 1024, sc, NN, nullptr, nullptr, 0,
        32, 16, NDIM, CDIM);
    // PV: OT[M=4096, Nn=512] -> GX=4, GY=32 (128x128)
    gemm4<3, 1><<<512, 256, 0, stream>>>(
        sc, NN, NDIM, vB, NC, NDIM, OT, NC, nullptr, nullptr, 0,
        4, 32, CDIM, NDIM);
  } else {
    // Fallback (~101 MB): per-batch rounds.
    for (int b = 0; b < BATCH; ++b) {
      gemm8n<2, 0><<<512, 512, 0, stream>>>(
          qkT + b * NQK, 0, 1024, qkT + b * NQK + 512, 0, 1024, sc, 0,
          nullptr, nullptr, 0, 32, 16, NDIM, CDIM);
      gemm4<3, 1><<<128, 256, 0, stream>>>(
          sc, 0, NDIM, vB + b * NC, 0, NDIM, OT + b * NC, 0,
          nullptr, nullptr, 0, 4, 32, CDIM, NDIM);
    }
  }

  // out = wp * OT^T + bp + x  (fp32 out, fused residual); wpb overlays dead qkT
  cvt_kernel<<<256, 256, 0, stream>>>(wp, wpb, 65536);
  gemm4<4, 1><<<512, 256, 0, stream>>>(
      wpb, 0, CDIM, OT, NC, CDIM, out, NC, bp, x, NC, 32, 4, NDIM, CDIM);
}